// Round 10
// baseline (282.085 us; speedup 1.0000x reference)
//
#include <hip/hip_runtime.h>

#define TSTEPS 15
#define HID    64
#define LAT    16
#define NBATCH 65536

typedef _Float16 v8h __attribute__((ext_vector_type(8)));
typedef _Float16 v4h __attribute__((ext_vector_type(4)));
typedef _Float16 v2h __attribute__((ext_vector_type(2)));
typedef float    v4f __attribute__((ext_vector_type(4)));

__device__ __forceinline__ float fast_sig(float x) {
    return __builtin_amdgcn_rcpf(1.0f + __expf(-x));
}
__device__ __forceinline__ float fast_tanh(float x) {
    return 2.0f * __builtin_amdgcn_rcpf(1.0f + __expf(-2.0f * x)) - 1.0f;
}

__device__ __forceinline__ v8h vzero8() {
    v8h v;
#pragma unroll
    for (int i = 0; i < 8; ++i) v[i] = (_Float16)0.0f;
    return v;
}

// v_cvt_pkrtz returns __fp16x2; bit-cast to our _Float16x2 (same bits).
__device__ __forceinline__ v4h pack4(float a, float b, float c, float d) {
    const v2h lo = __builtin_bit_cast(v2h, __builtin_amdgcn_cvt_pkrtz(a, b));
    const v2h hi = __builtin_bit_cast(v2h, __builtin_amdgcn_cvt_pkrtz(c, d));
    return __builtin_shufflevector(lo, hi, 0, 1, 2, 3);
}

// Software-pipelined fused 2-layer LSTM + FC, N=32 batch per wave.
//
// LOAD-BEARING (round 7): without the per-iteration asm memory clobber,
// LICM hoists all A-fragment ds_reads (448 VGPRs worth) out of the t-loop
// -> forced scratch spill -> 3-4 GB HBM scratch traffic. DO NOT REMOVE.
//
// Round-9 structure: L0(t+1) and L1(t) are mutually independent (L0 needs
// only h0(t); L1 needs h0(t), h1(t-1)), so one body computes both ->
// two independent MFMA/VALU streams per wave fill the 42% stall gap seen
// in round 8. Single state buffer suffices: per-wave LDS ops are ordered
// (write h0' -> read hf -> write h1 -> read gf); the C->B transpose works
// without barriers because wave lanes execute in lockstep.
// Also: FC done as 2 MFMAs on gf B-frags (row 0 = Wfc, rest zero);
// L0 bias folded into the z MFMA (z k=16 element = 1.0, bias as weight
// column, so plane-0 staging carries bih0+bhh0 at kk==16);
// f16 packing via v_cvt_pkrtz.
//
//   D[m=gate(256), n=batch(32)] = A[weights] * B[z | h0 | x | h1]
// wf planes: 0=Wih0(z,K16; k=16 -> bias; rest 0) 1,2=Whh0 3,4=Wih1 5,6=Whh1.
// Gate order (PyTorch): 0=i,1=f,2=g,3=o ; g = 64*type + u, u=16a+4q+r.
__global__ __launch_bounds__(512, 2) void lstm2_pipe(
        const float* __restrict__ z,
        const float* __restrict__ Wih0, const float* __restrict__ Whh0,
        const float* __restrict__ bih0, const float* __restrict__ bhh0,
        const float* __restrict__ Wih1, const float* __restrict__ Whh1,
        const float* __restrict__ bih1, const float* __restrict__ bhh1,
        const float* __restrict__ Wfc,  const float* __restrict__ bfc,
        float* __restrict__ out)
{
    __shared__ __align__(16) _Float16 wf[7 * 16 * 64 * 8];   // 114688 B
    __shared__ __align__(16) _Float16 wfcf[2 * 64 * 8];      //   2048 B
    __shared__ __align__(16) float    bsum1[256];            //   1024 B
    __shared__ __align__(16) _Float16 state[8][32 * 72];     //  36864 B
                                                             // 154624 B total

    const int tid  = threadIdx.x;
    const int wave = tid >> 6;           // 0..7
    const int lane = tid & 63;
    const int q    = lane >> 4;          // quad
    const int c    = lane & 15;          // batch col within group
    const int row0 = blockIdx.x * 256 + wave * 32;   // wave's batch base

    /* ---------------- one-time staging: weights + biases ----------------- */
#pragma unroll 4
    for (int e = tid; e < 7 * 16 * 64 * 8; e += 512) {
        const int j  = e & 7;
        const int lm = (e >> 3) & 63;
        const int mt = (e >> 9) & 15;
        const int p  = e >> 13;                  // fragment plane 0..6
        const int g  = mt * 16 + (lm & 15);      // gate row 0..255
        const int kk = (lm >> 4) * 8 + j;        // k within 32-chunk
        float v;
        if (p == 0)      v = (kk < LAT) ? Wih0[g * LAT + kk]
                           : (kk == LAT ? bih0[g] + bhh0[g] : 0.0f);
        else if (p == 1) v = Whh0[g * HID + kk];
        else if (p == 2) v = Whh0[g * HID + 32 + kk];
        else if (p == 3) v = Wih1[g * HID + kk];
        else if (p == 4) v = Wih1[g * HID + 32 + kk];
        else if (p == 5) v = Whh1[g * HID + kk];
        else             v = Whh1[g * HID + 32 + kk];
        wf[e] = (_Float16)v;
    }
    // FC A-fragments: row m=0 carries Wfc, rows 1..15 zero
#pragma unroll
    for (int e = tid; e < 2 * 64 * 8; e += 512) {
        const int j  = e & 7;
        const int lm = (e >> 3) & 63;
        const int kc = e >> 9;
        const int kk = kc * 32 + (lm >> 4) * 8 + j;
        wfcf[e] = ((lm & 15) == 0) ? (_Float16)Wfc[kk] : (_Float16)0.0f;
    }
    if (tid < 256) bsum1[tid] = bih1[tid] + bhh1[tid];
    __syncthreads();   // the only barrier in the kernel

    _Float16* stW = &state[wave][0];
    const float bfcv = bfc[0];

    // z B-fragments (constant over t); element k=16 = 1.0 multiplies the
    // bias column staged in plane 0.
    v8h zfrag[2];
#pragma unroll
    for (int n = 0; n < 2; ++n) {
        zfrag[n] = vzero8();
        if (q < 2) {
            const float* zp = z + (size_t)(row0 + 16 * n + c) * LAT + q * 8;
            const float4 za = *(const float4*)(zp);
            const float4 zb = *(const float4*)(zp + 4);
            zfrag[n][0] = (_Float16)za.x; zfrag[n][1] = (_Float16)za.y;
            zfrag[n][2] = (_Float16)za.z; zfrag[n][3] = (_Float16)za.w;
            zfrag[n][4] = (_Float16)zb.x; zfrag[n][5] = (_Float16)zb.y;
            zfrag[n][6] = (_Float16)zb.z; zfrag[n][7] = (_Float16)zb.w;
        }
        if (q == 2) zfrag[n][0] = (_Float16)1.0f;   // bias slot
    }

    v8h hf[2][2], gf[2][2];              // [group n][k-half] B-frags
    v4h h1pk[4][2];                      // packed h1 awaiting deferred write
    float c0s[2][16], c1s[2][16];
#pragma unroll
    for (int n = 0; n < 2; ++n) {
        hf[n][0] = vzero8(); hf[n][1] = vzero8();
        gf[n][0] = vzero8(); gf[n][1] = vzero8();
#pragma unroll
        for (int i = 0; i < 16; ++i) { c0s[n][i] = 0.0f; c1s[n][i] = 0.0f; }
    }

#define AFRAG(pl, mt) (*(const v8h*)&wf[(((pl) * 16 + (mt)) * 64 + lane) * 8])
#define MFMA16(A, B, C) __builtin_amdgcn_mfma_f32_16x16x32_f16((A), (B), (C), 0, 0, 0)

    // Pipelined: iteration tt computes L0 step tt (tt<15) and L1 step tt-1
    // (tt>0). Both depend only on register state at body entry -> the two
    // streams interleave freely.
#pragma unroll 1
    for (int tt = 0; tt <= TSTEPS; ++tt) {
        // Kill LICM (see header comment). Emits no instructions.
        __asm__ __volatile__("" ::: "memory");

        const bool do_l0 = (tt < TSTEPS);
        const bool do_l1 = (tt > 0);

#pragma unroll
        for (int a = 0; a < 4; ++a) {            // unit group u = 16a+4q+r
            v4f acc0[2][4], acc1[2][4];
            if (do_l0) {
#pragma unroll
                for (int ty = 0; ty < 4; ++ty) {
                    const int mt = 4 * ty + a;
                    const v8h a0 = AFRAG(0, mt);
                    const v8h a1 = AFRAG(1, mt);
                    const v8h a2 = AFRAG(2, mt);
                    v4f t0 = {0.f, 0.f, 0.f, 0.f};
                    v4f t1 = {0.f, 0.f, 0.f, 0.f};
                    t0 = MFMA16(a0, zfrag[0], t0);  t1 = MFMA16(a0, zfrag[1], t1);
                    t0 = MFMA16(a1, hf[0][0], t0);  t1 = MFMA16(a1, hf[1][0], t1);
                    t0 = MFMA16(a2, hf[0][1], t0);  t1 = MFMA16(a2, hf[1][1], t1);
                    acc0[0][ty] = t0;  acc0[1][ty] = t1;
                }
            }
            if (do_l1) {
#pragma unroll
                for (int ty = 0; ty < 4; ++ty) {
                    const int mt = 4 * ty + a;
                    const v4f b  = *(const v4f*)&bsum1[64 * ty + 16 * a + 4 * q];
                    const v8h a3 = AFRAG(3, mt);
                    const v8h a4 = AFRAG(4, mt);
                    const v8h a5 = AFRAG(5, mt);
                    const v8h a6 = AFRAG(6, mt);
                    v4f t0 = MFMA16(a3, hf[0][0], b);
                    v4f t1 = MFMA16(a3, hf[1][0], b);
                    t0 = MFMA16(a4, hf[0][1], t0);  t1 = MFMA16(a4, hf[1][1], t1);
                    t0 = MFMA16(a5, gf[0][0], t0);  t1 = MFMA16(a5, gf[1][0], t1);
                    t0 = MFMA16(a6, gf[0][1], t0);  t1 = MFMA16(a6, gf[1][1], t1);
                    acc1[0][ty] = t0;  acc1[1][ty] = t1;
                }
            }
            if (do_l0) {
#pragma unroll
                for (int n = 0; n < 2; ++n) {
                    float hh[4];
#pragma unroll
                    for (int r = 0; r < 4; ++r) {
                        const float ig = fast_sig(acc0[n][0][r]);
                        const float fg = fast_sig(acc0[n][1][r]);
                        const float gg = fast_tanh(acc0[n][2][r]);
                        const float og = fast_sig(acc0[n][3][r]);
                        const float cc = fg * c0s[n][a * 4 + r] + ig * gg;
                        c0s[n][a * 4 + r] = cc;
                        hh[r] = og * fast_tanh(cc);
                    }
                    *(v4h*)&stW[(c + 16 * n) * 72 + 16 * a + 4 * q] =
                        pack4(hh[0], hh[1], hh[2], hh[3]);
                }
            }
            if (do_l1) {
#pragma unroll
                for (int n = 0; n < 2; ++n) {
                    float hh[4];
#pragma unroll
                    for (int r = 0; r < 4; ++r) {
                        const float ig = fast_sig(acc1[n][0][r]);
                        const float fg = fast_sig(acc1[n][1][r]);
                        const float gg = fast_tanh(acc1[n][2][r]);
                        const float og = fast_sig(acc1[n][3][r]);
                        const float cc = fg * c1s[n][a * 4 + r] + ig * gg;
                        c1s[n][a * 4 + r] = cc;
                        hh[r] = og * fast_tanh(cc);
                    }
                    h1pk[a][n] = pack4(hh[0], hh[1], hh[2], hh[3]);
                }
            }
        }

        if (do_l0) {
            // read back h0(tt) as B-frags (registers; also x input next body)
#pragma unroll
            for (int n = 0; n < 2; ++n) {
                hf[n][0] = *(const v8h*)&stW[(c + 16 * n) * 72 + 8 * q];
                hf[n][1] = *(const v8h*)&stW[(c + 16 * n) * 72 + 32 + 8 * q];
            }
        }
        if (do_l1) {
            // deferred h1 writes (state buffer free now hf is in regs)
#pragma unroll
            for (int a = 0; a < 4; ++a)
#pragma unroll
                for (int n = 0; n < 2; ++n)
                    *(v4h*)&stW[(c + 16 * n) * 72 + 16 * a + 4 * q] = h1pk[a][n];
#pragma unroll
            for (int n = 0; n < 2; ++n) {
                gf[n][0] = *(const v8h*)&stW[(c + 16 * n) * 72 + 8 * q];
                gf[n][1] = *(const v8h*)&stW[(c + 16 * n) * 72 + 32 + 8 * q];
            }
            // FC as MFMA: row 0 of wfcf = Wfc -> D row 0 = lanes 0..15, reg 0
            const v8h w0 = *(const v8h*)&wfcf[(0 * 64 + lane) * 8];
            const v8h w1 = *(const v8h*)&wfcf[(1 * 64 + lane) * 8];
#pragma unroll
            for (int n = 0; n < 2; ++n) {
                v4f f = {0.f, 0.f, 0.f, 0.f};
                f = MFMA16(w0, gf[n][0], f);
                f = MFMA16(w1, gf[n][1], f);
                if (lane < 16)
                    out[(size_t)(row0 + 16 * n + lane) * TSTEPS + (tt - 1)] = f[0] + bfcv;
            }
        }
    }
#undef AFRAG
#undef MFMA16
}

extern "C" void kernel_launch(void* const* d_in, const int* in_sizes, int n_in,
                              void* d_out, int out_size, void* d_ws, size_t ws_size,
                              hipStream_t stream)
{
    (void)in_sizes; (void)n_in; (void)out_size; (void)d_ws; (void)ws_size;

    const float* z    = (const float*)d_in[0];
    const float* Wih0 = (const float*)d_in[1];
    const float* Whh0 = (const float*)d_in[2];
    const float* bih0 = (const float*)d_in[3];
    const float* bhh0 = (const float*)d_in[4];
    const float* Wih1 = (const float*)d_in[5];
    const float* Whh1 = (const float*)d_in[6];
    const float* bih1 = (const float*)d_in[7];
    const float* bhh1 = (const float*)d_in[8];
    const float* Wfc  = (const float*)d_in[9];
    const float* bfc  = (const float*)d_in[10];

    lstm2_pipe<<<dim3(NBATCH / 256), dim3(512), 0, stream>>>(
        z, Wih0, Whh0, bih0, bhh0, Wih1, Whh1, bih1, bhh1, Wfc, bfc,
        (float*)d_out);
}

// Round 11
// 271.789 us; speedup vs baseline: 1.0379x; 1.0379x over previous
//
#include <hip/hip_runtime.h>

#define TSTEPS 15
#define HID    64
#define LAT    16
#define NBATCH 65536

typedef _Float16 v8h __attribute__((ext_vector_type(8)));
typedef _Float16 v4h __attribute__((ext_vector_type(4)));
typedef _Float16 v2h __attribute__((ext_vector_type(2)));
typedef float    v4f __attribute__((ext_vector_type(4)));

__device__ __forceinline__ float fast_sig(float x) {
    return __builtin_amdgcn_rcpf(1.0f + __expf(-x));
}
__device__ __forceinline__ float fast_tanh(float x) {
    return 2.0f * __builtin_amdgcn_rcpf(1.0f + __expf(-2.0f * x)) - 1.0f;
}

__device__ __forceinline__ v8h vzero8() {
    v8h v;
#pragma unroll
    for (int i = 0; i < 8; ++i) v[i] = (_Float16)0.0f;
    return v;
}

// v_cvt_pkrtz returns __fp16x2; bit-cast to our _Float16x2 (same bits).
__device__ __forceinline__ v4h pack4(float a, float b, float c, float d) {
    const v2h lo = __builtin_bit_cast(v2h, __builtin_amdgcn_cvt_pkrtz(a, b));
    const v2h hi = __builtin_bit_cast(v2h, __builtin_amdgcn_cvt_pkrtz(c, d));
    return __builtin_shufflevector(lo, hi, 0, 1, 2, 3);
}

// Software-pipelined fused 2-layer LSTM + FC, N=32 batch per wave.
//
// LOAD-BEARING (round 7): without the per-iteration asm memory clobber,
// LICM hoists all A-fragment ds_reads (448 VGPRs worth) out of the t-loop
// -> forced scratch spill -> 3-4 GB HBM scratch traffic. DO NOT REMOVE.
//
// Round-11 structure: round 10 put the independent L0(t)/L1(t-1) streams
// in separate basic blocks (if(do_l0)/if(do_l1)) -> the machine scheduler
// could not interleave them -> zero gain. Now the steady-state body
// (tt=1..14) is UNCONDITIONAL straight-line code (one BB, both streams),
// with peeled L0-only prologue and L1-only epilogue. amdgpu_waves_per_eu(2,2)
// grants the 256-VGPR budget (2 waves/EU) so the scheduler has headroom to
// actually interleave; spill tripwire = WRITE_SIZE (must stay ~3.84 MB).
//
// LDS state machine per body (per wave, ordered same-wave ds ops):
//   write h0(tt) -> read hf -> write h1(tt-1) -> read gf -> FC MFMA.
// L1's MFMAs consume hf/gf from REGISTERS (last iteration), so they are
// independent of this body's LDS traffic and of L0's MFMAs.
//
//   D[m=gate(256), n=batch(32)] = A[weights] * B[z | h0 | x | h1]
// wf planes: 0=Wih0(z,K16; k=16 -> bias; rest 0) 1,2=Whh0 3,4=Wih1 5,6=Whh1.
// Gate order (PyTorch): 0=i,1=f,2=g,3=o ; g = 64*type + u, u=16a+4q+r;
// acc[n][ty] -> ty IS the gate type (mt = 4*ty+a).
__global__ __launch_bounds__(512)
__attribute__((amdgpu_waves_per_eu(2, 2)))
void lstm2_pipe2(
        const float* __restrict__ z,
        const float* __restrict__ Wih0, const float* __restrict__ Whh0,
        const float* __restrict__ bih0, const float* __restrict__ bhh0,
        const float* __restrict__ Wih1, const float* __restrict__ Whh1,
        const float* __restrict__ bih1, const float* __restrict__ bhh1,
        const float* __restrict__ Wfc,  const float* __restrict__ bfc,
        float* __restrict__ out)
{
    __shared__ __align__(16) _Float16 wf[7 * 16 * 64 * 8];   // 114688 B
    __shared__ __align__(16) _Float16 wfcf[2 * 64 * 8];      //   2048 B
    __shared__ __align__(16) float    bsum1[256];            //   1024 B
    __shared__ __align__(16) _Float16 state[8][32 * 72];     //  36864 B
                                                             // 154624 B total

    const int tid  = threadIdx.x;
    const int wave = tid >> 6;           // 0..7
    const int lane = tid & 63;
    const int q    = lane >> 4;          // quad
    const int c    = lane & 15;          // batch col within group
    const int row0 = blockIdx.x * 256 + wave * 32;   // wave's batch base

    /* ---------------- one-time staging: weights + biases ----------------- */
#pragma unroll 4
    for (int e = tid; e < 7 * 16 * 64 * 8; e += 512) {
        const int j  = e & 7;
        const int lm = (e >> 3) & 63;
        const int mt = (e >> 9) & 15;
        const int p  = e >> 13;                  // fragment plane 0..6
        const int g  = mt * 16 + (lm & 15);      // gate row 0..255
        const int kk = (lm >> 4) * 8 + j;        // k within 32-chunk
        float v;
        if (p == 0)      v = (kk < LAT) ? Wih0[g * LAT + kk]
                           : (kk == LAT ? bih0[g] + bhh0[g] : 0.0f);
        else if (p == 1) v = Whh0[g * HID + kk];
        else if (p == 2) v = Whh0[g * HID + 32 + kk];
        else if (p == 3) v = Wih1[g * HID + kk];
        else if (p == 4) v = Wih1[g * HID + 32 + kk];
        else if (p == 5) v = Whh1[g * HID + kk];
        else             v = Whh1[g * HID + 32 + kk];
        wf[e] = (_Float16)v;
    }
    // FC A-fragments: row m=0 carries Wfc, rows 1..15 zero
#pragma unroll
    for (int e = tid; e < 2 * 64 * 8; e += 512) {
        const int j  = e & 7;
        const int lm = (e >> 3) & 63;
        const int kc = e >> 9;
        const int kk = kc * 32 + (lm >> 4) * 8 + j;
        wfcf[e] = ((lm & 15) == 0) ? (_Float16)Wfc[kk] : (_Float16)0.0f;
    }
    if (tid < 256) bsum1[tid] = bih1[tid] + bhh1[tid];
    __syncthreads();   // the only barrier in the kernel

    _Float16* stW = &state[wave][0];
    const float bfcv = bfc[0];

    // z B-fragments (constant over t); element k=16 = 1.0 multiplies the
    // bias column staged in plane 0.
    v8h zfrag[2];
#pragma unroll
    for (int n = 0; n < 2; ++n) {
        zfrag[n] = vzero8();
        if (q < 2) {
            const float* zp = z + (size_t)(row0 + 16 * n + c) * LAT + q * 8;
            const float4 za = *(const float4*)(zp);
            const float4 zb = *(const float4*)(zp + 4);
            zfrag[n][0] = (_Float16)za.x; zfrag[n][1] = (_Float16)za.y;
            zfrag[n][2] = (_Float16)za.z; zfrag[n][3] = (_Float16)za.w;
            zfrag[n][4] = (_Float16)zb.x; zfrag[n][5] = (_Float16)zb.y;
            zfrag[n][6] = (_Float16)zb.z; zfrag[n][7] = (_Float16)zb.w;
        }
        if (q == 2) zfrag[n][0] = (_Float16)1.0f;   // bias slot
    }

    v8h hf[2][2], gf[2][2];              // [group n][k-half] B-frags
    v4h h1pk[4][2];                      // packed h1 awaiting deferred write
    float c0s[2][16], c1s[2][16];
#pragma unroll
    for (int n = 0; n < 2; ++n) {
        hf[n][0] = vzero8(); hf[n][1] = vzero8();
        gf[n][0] = vzero8(); gf[n][1] = vzero8();
#pragma unroll
        for (int i = 0; i < 16; ++i) { c0s[n][i] = 0.0f; c1s[n][i] = 0.0f; }
    }

#define AFRAG(pl, mt) (*(const v8h*)&wf[(((pl) * 16 + (mt)) * 64 + lane) * 8])
#define MFMA16(A, B, C) __builtin_amdgcn_mfma_f32_16x16x32_f16((A), (B), (C), 0, 0, 0)

    // ---- stream pieces (inlined lambdas; each call site is straight-line
    // code, so inside the merged loop body both streams share one BB) ----

    auto l0_part = [&]() {   // L0 MFMAs + epilogue + h0 stores (uses old hf)
#pragma unroll
        for (int a = 0; a < 4; ++a) {
            v4f acc0[2][4];
#pragma unroll
            for (int ty = 0; ty < 4; ++ty) {
                const int mt = 4 * ty + a;
                const v8h a0 = AFRAG(0, mt);
                const v8h a1 = AFRAG(1, mt);
                const v8h a2 = AFRAG(2, mt);
                v4f t0 = {0.f, 0.f, 0.f, 0.f};
                v4f t1 = {0.f, 0.f, 0.f, 0.f};
                t0 = MFMA16(a0, zfrag[0], t0);  t1 = MFMA16(a0, zfrag[1], t1);
                t0 = MFMA16(a1, hf[0][0], t0);  t1 = MFMA16(a1, hf[1][0], t1);
                t0 = MFMA16(a2, hf[0][1], t0);  t1 = MFMA16(a2, hf[1][1], t1);
                acc0[0][ty] = t0;  acc0[1][ty] = t1;
            }
#pragma unroll
            for (int n = 0; n < 2; ++n) {
                float hh[4];
#pragma unroll
                for (int r = 0; r < 4; ++r) {
                    const float ig = fast_sig(acc0[n][0][r]);
                    const float fg = fast_sig(acc0[n][1][r]);
                    const float gg = fast_tanh(acc0[n][2][r]);
                    const float og = fast_sig(acc0[n][3][r]);
                    const float cc = fg * c0s[n][a * 4 + r] + ig * gg;
                    c0s[n][a * 4 + r] = cc;
                    hh[r] = og * fast_tanh(cc);
                }
                *(v4h*)&stW[(c + 16 * n) * 72 + 16 * a + 4 * q] =
                    pack4(hh[0], hh[1], hh[2], hh[3]);
            }
        }
    };

    auto l1_part = [&]() {   // L1 MFMAs + epilogue -> h1pk (uses old hf, gf)
#pragma unroll
        for (int a = 0; a < 4; ++a) {
            v4f acc1[2][4];
#pragma unroll
            for (int ty = 0; ty < 4; ++ty) {
                const int mt = 4 * ty + a;
                const v4f b  = *(const v4f*)&bsum1[64 * ty + 16 * a + 4 * q];
                const v8h a3 = AFRAG(3, mt);
                const v8h a4 = AFRAG(4, mt);
                const v8h a5 = AFRAG(5, mt);
                const v8h a6 = AFRAG(6, mt);
                v4f t0 = MFMA16(a3, hf[0][0], b);
                v4f t1 = MFMA16(a3, hf[1][0], b);
                t0 = MFMA16(a4, hf[0][1], t0);  t1 = MFMA16(a4, hf[1][1], t1);
                t0 = MFMA16(a5, gf[0][0], t0);  t1 = MFMA16(a5, gf[1][0], t1);
                t0 = MFMA16(a6, gf[0][1], t0);  t1 = MFMA16(a6, gf[1][1], t1);
                acc1[0][ty] = t0;  acc1[1][ty] = t1;
            }
#pragma unroll
            for (int n = 0; n < 2; ++n) {
                float hh[4];
#pragma unroll
                for (int r = 0; r < 4; ++r) {
                    const float ig = fast_sig(acc1[n][0][r]);
                    const float fg = fast_sig(acc1[n][1][r]);
                    const float gg = fast_tanh(acc1[n][2][r]);
                    const float og = fast_sig(acc1[n][3][r]);
                    const float cc = fg * c1s[n][a * 4 + r] + ig * gg;
                    c1s[n][a * 4 + r] = cc;
                    hh[r] = og * fast_tanh(cc);
                }
                h1pk[a][n] = pack4(hh[0], hh[1], hh[2], hh[3]);
            }
        }
    };

    auto l0_finish = [&]() {   // pull new h0 into B-frag registers
#pragma unroll
        for (int n = 0; n < 2; ++n) {
            hf[n][0] = *(const v8h*)&stW[(c + 16 * n) * 72 + 8 * q];
            hf[n][1] = *(const v8h*)&stW[(c + 16 * n) * 72 + 32 + 8 * q];
        }
    };

    auto l1_finish = [&](int trow) {   // h1 store, gf reload, FC, out
#pragma unroll
        for (int a = 0; a < 4; ++a)
#pragma unroll
            for (int n = 0; n < 2; ++n)
                *(v4h*)&stW[(c + 16 * n) * 72 + 16 * a + 4 * q] = h1pk[a][n];
#pragma unroll
        for (int n = 0; n < 2; ++n) {
            gf[n][0] = *(const v8h*)&stW[(c + 16 * n) * 72 + 8 * q];
            gf[n][1] = *(const v8h*)&stW[(c + 16 * n) * 72 + 32 + 8 * q];
        }
        const v8h w0 = *(const v8h*)&wfcf[(0 * 64 + lane) * 8];
        const v8h w1 = *(const v8h*)&wfcf[(1 * 64 + lane) * 8];
#pragma unroll
        for (int n = 0; n < 2; ++n) {
            v4f f = {0.f, 0.f, 0.f, 0.f};
            f = MFMA16(w0, gf[n][0], f);
            f = MFMA16(w1, gf[n][1], f);
            if (lane < 16)
                out[(size_t)(row0 + 16 * n + lane) * TSTEPS + trow] = f[0] + bfcv;
        }
    };

    /* --------------------------- pipeline --------------------------- */
    l0_part();          // L0 step 0 (hf, gf are zero)
    l0_finish();

#pragma unroll 1
    for (int tt = 1; tt < TSTEPS; ++tt) {
        // Kill LICM (see header comment). Emits no instructions.
        __asm__ __volatile__("" ::: "memory");
        // Merged body, ONE basic block: L0(tt) and L1(tt-1) both consume
        // the register-resident hf/gf from the previous iteration.
        l0_part();           // writes h0(tt) to stW
        l1_part();           // -> h1pk (registers only)
        l0_finish();         // hf <- h0(tt)
        l1_finish(tt - 1);   // h1 store, gf <- h1(tt-1), FC, out row tt-1
    }

    __asm__ __volatile__("" ::: "memory");
    l1_part();          // L1 step 14
    l1_finish(TSTEPS - 1);

#undef AFRAG
#undef MFMA16
}

extern "C" void kernel_launch(void* const* d_in, const int* in_sizes, int n_in,
                              void* d_out, int out_size, void* d_ws, size_t ws_size,
                              hipStream_t stream)
{
    (void)in_sizes; (void)n_in; (void)out_size; (void)d_ws; (void)ws_size;

    const float* z    = (const float*)d_in[0];
    const float* Wih0 = (const float*)d_in[1];
    const float* Whh0 = (const float*)d_in[2];
    const float* bih0 = (const float*)d_in[3];
    const float* bhh0 = (const float*)d_in[4];
    const float* Wih1 = (const float*)d_in[5];
    const float* Whh1 = (const float*)d_in[6];
    const float* bih1 = (const float*)d_in[7];
    const float* bhh1 = (const float*)d_in[8];
    const float* Wfc  = (const float*)d_in[9];
    const float* bfc  = (const float*)d_in[10];

    lstm2_pipe2<<<dim3(NBATCH / 256), dim3(512), 0, stream>>>(
        z, Wih0, Whh0, bih0, bhh0, Wih1, Whh1, bih1, bhh1, Wfc, bfc,
        (float*)d_out);
}